// Round 15
// baseline (107.775 us; speedup 1.0000x reference)
//
#include <hip/hip_runtime.h>

#define NPTS   4096
#define BQ     16
#define NT     512               // 8 waves per block
#define NTILES (NPTS / 32)       // 128 inner tiles of 32 points
#define WC     2                 // column-tiles (32 cols) per wave
#define BCOLS  512               // cols per block (8 waves x 64)
#define NBLK   256               // 1 block/CU, single dispatch round

typedef short bhalf8   __attribute__((ext_vector_type(8)));   // 8 bf16 (4 VGPRs)
typedef float floatx16 __attribute__((ext_vector_type(16)));  // 32x32 MFMA acc

__device__ __forceinline__ short f2bf(float f) {
    unsigned u = __float_as_uint(f);
    unsigned r = (u + 0x7FFFu + ((u >> 16) & 1u)) >> 16;   // RNE
    return (short)r;
}
__device__ __forceinline__ float bf2f(short s) {
    return __uint_as_float(((unsigned)(unsigned short)s) << 16);
}
__device__ __forceinline__ int imin(int a, int b) { return a < b ? a : b; }

// MODE 0: production (R14-verified). MODE 1: ablation — min-tree replaced by
// a single imin on c[0] (MFMA stays live, ~7/8 of epilogue VALU removed).
// Ablation launches write only to scratch acc/out.
template<int MODE>
__global__ __launch_bounds__(NT, 1)
void chamfer_fused_kernel(const float* __restrict__ preds,
                          const float* __restrict__ gts,
                          unsigned long long* __restrict__ acc,
                          float* __restrict__ out)
{
    __shared__ bhalf8 s_frag[NTILES * 32];   // 64 KB

    const int tid = (int)threadIdx.x;
    const int cb  = blockIdx.x;   // 0..7
    const int bd  = blockIdx.y;   // 0..31
    const int dir = bd >> 4;
    const int b   = bd & 15;

    const float* outer = (dir == 0) ? preds : gts;
    const float* inner = (dir == 0) ? gts   : preds;
    const float* ob = outer + (size_t)b * NPTS * 3;
    const float* ib = inner + (size_t)b * NPTS * 3;

    const short one = (short)0x3F80;   // bf16 1.0

    // ---- stage ALL inner points once (e0 form only) ----
    for (int p = tid; p < NPTS; p += NT) {
        const float x0 = ib[p * 3 + 0], x1 = ib[p * 3 + 1], x2 = ib[p * 3 + 2];
        const float a0 = -2.0f * x0, a1 = -2.0f * x1, a2 = -2.0f * x2;
        const short h0 = f2bf(a0), h1 = f2bf(a1), h2 = f2bf(a2);
        const short l0 = f2bf(a0 - bf2f(h0));
        const short l1 = f2bf(a1 - bf2f(h1));
        const short l2 = f2bf(a2 - bf2f(h2));
        const float xx = x0 * x0 + x1 * x1 + x2 * x2;
        const short xh = f2bf(xx);
        const short xl = f2bf(xx - bf2f(xh));
        bhalf8 e0;
        e0[0] = h0; e0[1] = h1; e0[2] = h2; e0[3] = l0;
        e0[4] = l1; e0[5] = l2; e0[6] = xh; e0[7] = xl;
        s_frag[(p >> 5) * 32 + (p & 31)] = e0;
    }

    const int wv   = tid >> 6;           // 0..7
    const int lane = tid & 63;
    const int g    = lane >> 5;          // k-group 0..1
    const int colbase = cb * BCOLS + wv * (WC * 32);

    bhalf8 bfrag[WC];
#pragma unroll
    for (int ct = 0; ct < WC; ++ct) {
        const int col = colbase + ct * 32 + (lane & 31);
        const float y0 = ob[col * 3 + 0], y1 = ob[col * 3 + 1], y2 = ob[col * 3 + 2];
        const short h0 = f2bf(y0), h1 = f2bf(y1), h2 = f2bf(y2);
        bhalf8 f;
        if (g == 0) {          // k 0-7: [yh(3), yh(3), 1, 1]
            f[0] = h0; f[1] = h1; f[2] = h2; f[3] = h0; f[4] = h1; f[5] = h2;
            f[6] = one; f[7] = one;
        } else {               // k 8-15: [yl(3), yl(3), vh, vl], v = yy + 1
            const short q0 = f2bf(y0 - bf2f(h0));
            const short q1 = f2bf(y1 - bf2f(h1));
            const short q2 = f2bf(y2 - bf2f(h2));
            const float v = y0 * y0 + y1 * y1 + y2 * y2 + 1.0f;
            const short vh = f2bf(v);
            const short vl = f2bf(v - bf2f(vh));
            f[0] = q0; f[1] = q1; f[2] = q2; f[3] = q0; f[4] = q1; f[5] = q2;
            f[6] = vh; f[7] = vl;
        }
        bfrag[ct] = f;
    }
    __syncthreads();

    int accm[WC];
#pragma unroll
    for (int ct = 0; ct < WC; ++ct) accm[ct] = 0x7F7F7F7F;

    const floatx16 zacc = {0,0,0,0,0,0,0,0,0,0,0,0,0,0,0,0};
    const int onepair = 0x3F803F80;   // two bf16 1.0

#pragma unroll 2
    for (int t = 0; t < NTILES; ++t) {
        union { bhalf8 v; int4 i; } au;
        au.v = s_frag[t * 32 + (lane & 31)];
        if (lane >= 32) au.i.w = onepair;      // slots 6,7 -> 1.0,1.0 (== e1)
        const bhalf8 a = au.v;
#pragma unroll
        for (int ct = 0; ct < WC; ++ct) {
            const floatx16 c = __builtin_amdgcn_mfma_f32_32x32x16_bf16(a, bfrag[ct], zacc, 0, 0, 0);
            if (MODE == 0) {
                const int x0  = __float_as_int(c[0]),  x1  = __float_as_int(c[1]);
                const int x2  = __float_as_int(c[2]),  x3  = __float_as_int(c[3]);
                const int x4  = __float_as_int(c[4]),  x5  = __float_as_int(c[5]);
                const int x6  = __float_as_int(c[6]),  x7  = __float_as_int(c[7]);
                const int x8  = __float_as_int(c[8]),  x9  = __float_as_int(c[9]);
                const int x10 = __float_as_int(c[10]), x11 = __float_as_int(c[11]);
                const int x12 = __float_as_int(c[12]), x13 = __float_as_int(c[13]);
                const int x14 = __float_as_int(c[14]), x15 = __float_as_int(c[15]);
                const int ta = imin(imin(x0,  x1),  x2);
                const int tb = imin(imin(x3,  x4),  x5);
                const int tc = imin(imin(x6,  x7),  x8);
                const int td = imin(imin(x9,  x10), x11);
                const int te = imin(imin(x12, x13), x14);
                const int tf = imin(imin(ta, tb), x15);
                const int tg = imin(imin(tc, td), te);
                accm[ct] = imin(imin(tf, tg), accm[ct]);
            } else {
                // ablation: single consumer keeps the MFMA live, drops the tree
                accm[ct] = imin(accm[ct], __float_as_int(c[0]));
            }
        }
    }

    float msum = 0.0f;
#pragma unroll
    for (int ct = 0; ct < WC; ++ct) {
        int v = accm[ct];
        v = imin(v, __shfl_xor(v, 32, 64));
        if (lane < 32) msum += __int_as_float(v);
    }

    __syncthreads();
    float* s_red = (float*)s_frag;
    s_red[tid] = msum;
    __syncthreads();
#pragma unroll
    for (int s = NT / 2; s > 0; s >>= 1) {
        if (tid < s) s_red[tid] += s_red[tid + s];
        __syncthreads();
    }
    if (tid == 0) {
        const long long fx = (long long)llrint((double)s_red[0] * 4294967296.0);
        atomicAdd(&acc[0], (unsigned long long)fx);
        __threadfence();
        const unsigned long long t = atomicAdd(&acc[1], 1ULL);
        if (t == (unsigned long long)(NBLK - 1)) {
            const unsigned long long total = atomicAdd(&acc[0], 0ULL);
            const double v = (double)(long long)total *
                             (1.0 / 4294967296.0) * (1.0 / (double)(BQ * NPTS)) - 2.0;
            out[0] = (float)v;
        }
    }
}

extern "C" void kernel_launch(void* const* d_in, const int* in_sizes, int n_in,
                              void* d_out, int out_size, void* d_ws, size_t ws_size,
                              hipStream_t stream)
{
    const float* preds = (const float*)d_in[0];
    const float* gts   = (const float*)d_in[1];
    float* out = (float*)d_out;
    unsigned long long* acc  = (unsigned long long*)d_ws;    // [0,1] prod
    unsigned long long* acc2 = acc + 2;                      // [0,1] ablation
    float* scratch_out = (float*)(acc + 4);

    hipMemsetAsync(acc, 0, 4 * sizeof(unsigned long long), stream);

    dim3 grid(NPTS / BCOLS, 2 * BQ);   // (8, 32) = 256 blocks

    // 4x ablation (MODE 1) to scratch — timing probe
    chamfer_fused_kernel<1><<<grid, NT, 0, stream>>>(preds, gts, acc2, scratch_out);
    chamfer_fused_kernel<1><<<grid, NT, 0, stream>>>(preds, gts, acc2, scratch_out);
    chamfer_fused_kernel<1><<<grid, NT, 0, stream>>>(preds, gts, acc2, scratch_out);
    chamfer_fused_kernel<1><<<grid, NT, 0, stream>>>(preds, gts, acc2, scratch_out);

    // production (MODE 0)
    chamfer_fused_kernel<0><<<grid, NT, 0, stream>>>(preds, gts, acc, out);
}

// Round 16
// 28.767 us; speedup vs baseline: 3.7465x; 3.7465x over previous
//
#include <hip/hip_runtime.h>

#define NPTS   4096
#define BQ     16
#define NT     256               // 4 waves per block
#define SEG    2                 // inner segments
#define SEGN   (NPTS / SEG)      // 2048 inner points per block
#define NTL    (SEGN / 32)       // 64 tiles of 32 points
#define BCOLS  256               // cols per block (4 waves x 64)
#define NCOMB  128

typedef short bhalf8   __attribute__((ext_vector_type(8)));   // 8 bf16 (4 VGPRs)
typedef float floatx16 __attribute__((ext_vector_type(16)));  // 32x32 MFMA acc

__device__ __forceinline__ short f2bf(float f) {
    unsigned u = __float_as_uint(f);
    unsigned r = (u + 0x7FFFu + ((u >> 16) & 1u)) >> 16;   // RNE
    return (short)r;
}
__device__ __forceinline__ float bf2f(short s) {
    return __uint_as_float(((unsigned)(unsigned short)s) << 16);
}
__device__ __forceinline__ int imin(int a, int b) { return a < b ? a : b; }

__device__ __forceinline__ int treemin16(const floatx16 c, int accm) {
    const int x0  = __float_as_int(c[0]),  x1  = __float_as_int(c[1]);
    const int x2  = __float_as_int(c[2]),  x3  = __float_as_int(c[3]);
    const int x4  = __float_as_int(c[4]),  x5  = __float_as_int(c[5]);
    const int x6  = __float_as_int(c[6]),  x7  = __float_as_int(c[7]);
    const int x8  = __float_as_int(c[8]),  x9  = __float_as_int(c[9]);
    const int x10 = __float_as_int(c[10]), x11 = __float_as_int(c[11]);
    const int x12 = __float_as_int(c[12]), x13 = __float_as_int(c[13]);
    const int x14 = __float_as_int(c[14]), x15 = __float_as_int(c[15]);
    const int ta = imin(imin(x0,  x1),  x2);
    const int tb = imin(imin(x3,  x4),  x5);
    const int tc = imin(imin(x6,  x7),  x8);
    const int td = imin(imin(x9,  x10), x11);
    const int te = imin(imin(x12, x13), x14);
    const int tf = imin(imin(ta, tb), x15);
    const int tg = imin(imin(tc, td), te);
    return imin(imin(tf, tg), accm);
}

// Pass 1: MFMA 32x32x16 split-bf16 (R13/R14-verified math: D = dist2 + 1,
// positive -> int-bit min). SOFTWARE-PIPELINED consume: the min-tree of
// tile t runs AFTER the MFMA of tile t+1 is issued (static names p0*/p1*,
// no runtime-indexed arrays). 4 waves/block, 4 blocks/CU -> 4 waves/SIMD.
// grid (16, 2, 32) = 1024 blocks. Block (0,0,0) zeroes acc for pass 2.
__global__ __launch_bounds__(NT, 4)
void chamfer_mfma_kernel(const float* __restrict__ preds,
                         const float* __restrict__ gts,
                         unsigned int* __restrict__ partial,
                         unsigned long long* __restrict__ acc)
{
    __shared__ bhalf8 s_frag[NTL * 32];   // 32 KB

    const int tid = (int)threadIdx.x;
    const int cb  = blockIdx.x;   // 0..15
    const int seg = blockIdx.y;   // 0..1
    const int bd  = blockIdx.z;   // 0..31
    const int dir = bd >> 4;
    const int b   = bd & 15;

    if (cb == 0 && seg == 0 && bd == 0 && tid < 2)
        acc[tid] = 0ULL;   // [0]=fixed-point sum, [1]=ticket

    const float* outer = (dir == 0) ? preds : gts;
    const float* inner = (dir == 0) ? gts   : preds;
    const float* ob = outer + (size_t)b * NPTS * 3;
    const float* ib = inner + (size_t)b * NPTS * 3 + (size_t)seg * SEGN * 3;

    const short one = (short)0x3F80;   // bf16 1.0

    // ---- stage this segment's inner points (e0 form) ----
    for (int p = tid; p < SEGN; p += NT) {
        const float x0 = ib[p * 3 + 0], x1 = ib[p * 3 + 1], x2 = ib[p * 3 + 2];
        const float a0 = -2.0f * x0, a1 = -2.0f * x1, a2 = -2.0f * x2;
        const short h0 = f2bf(a0), h1 = f2bf(a1), h2 = f2bf(a2);
        const short l0 = f2bf(a0 - bf2f(h0));
        const short l1 = f2bf(a1 - bf2f(h1));
        const short l2 = f2bf(a2 - bf2f(h2));
        const float xx = x0 * x0 + x1 * x1 + x2 * x2;
        const short xh = f2bf(xx);
        const short xl = f2bf(xx - bf2f(xh));
        bhalf8 e0;
        e0[0] = h0; e0[1] = h1; e0[2] = h2; e0[3] = l0;
        e0[4] = l1; e0[5] = l2; e0[6] = xh; e0[7] = xl;
        s_frag[(p >> 5) * 32 + (p & 31)] = e0;
    }

    const int wv   = tid >> 6;           // 0..3
    const int lane = tid & 63;
    const int g    = lane >> 5;          // k-group 0..1
    const int colbase = cb * BCOLS + wv * 64;

    // ---- persistent B fragments: 2 col-tiles per wave (static names) ----
    bhalf8 bf0, bf1;
    {
        const int c0 = colbase + (lane & 31);
        const int c1 = c0 + 32;
#pragma unroll
        for (int k = 0; k < 2; ++k) {
            const int col = k ? c1 : c0;
            const float y0 = ob[col * 3 + 0], y1 = ob[col * 3 + 1], y2 = ob[col * 3 + 2];
            const short h0 = f2bf(y0), h1 = f2bf(y1), h2 = f2bf(y2);
            bhalf8 f;
            if (g == 0) {          // k 0-7: [yh(3), yh(3), 1, 1]
                f[0] = h0; f[1] = h1; f[2] = h2; f[3] = h0; f[4] = h1; f[5] = h2;
                f[6] = one; f[7] = one;
            } else {               // k 8-15: [yl(3), yl(3), vh, vl], v = yy+1
                const short q0 = f2bf(y0 - bf2f(h0));
                const short q1 = f2bf(y1 - bf2f(h1));
                const short q2 = f2bf(y2 - bf2f(h2));
                const float v = y0 * y0 + y1 * y1 + y2 * y2 + 1.0f;
                const short vh = f2bf(v);
                const short vl = f2bf(v - bf2f(vh));
                f[0] = q0; f[1] = q1; f[2] = q2; f[3] = q0; f[4] = q1; f[5] = q2;
                f[6] = vh; f[7] = vl;
            }
            if (k) bf1 = f; else bf0 = f;
        }
    }
    __syncthreads();

    int accm0 = 0x7F7F7F7F, accm1 = 0x7F7F7F7F;
    const floatx16 zacc = {0,0,0,0,0,0,0,0,0,0,0,0,0,0,0,0};
    const int onepair = 0x3F803F80;
    const int arow = lane & 31;

#define LOAD_A(dst, t)                                   \
    {                                                    \
        union { bhalf8 v; int4 i; } au_;                 \
        au_.v = s_frag[(t) * 32 + arow];                 \
        if (lane >= 32) au_.i.w = onepair;               \
        dst = au_.v;                                     \
    }

    // ---- software-pipelined main loop: consume tile t AFTER issuing t+1 ----
    bhalf8 a0, a1;
    floatx16 p0A, p0B, p1A, p1B;

    LOAD_A(a0, 0);
    p0A = __builtin_amdgcn_mfma_f32_32x32x16_bf16(a0, bf0, zacc, 0, 0, 0);
    p0B = __builtin_amdgcn_mfma_f32_32x32x16_bf16(a0, bf1, zacc, 0, 0, 0);

#pragma unroll 1
    for (int t = 1; t < NTL - 1; t += 2) {
        LOAD_A(a1, t);
        p1A = __builtin_amdgcn_mfma_f32_32x32x16_bf16(a1, bf0, zacc, 0, 0, 0);
        p1B = __builtin_amdgcn_mfma_f32_32x32x16_bf16(a1, bf1, zacc, 0, 0, 0);
        accm0 = treemin16(p0A, accm0);
        accm1 = treemin16(p0B, accm1);
        LOAD_A(a0, t + 1);
        p0A = __builtin_amdgcn_mfma_f32_32x32x16_bf16(a0, bf0, zacc, 0, 0, 0);
        p0B = __builtin_amdgcn_mfma_f32_32x32x16_bf16(a0, bf1, zacc, 0, 0, 0);
        accm0 = treemin16(p1A, accm0);
        accm1 = treemin16(p1B, accm1);
    }
    // epilogue: last tile (NTL-1), then drain both stages
    LOAD_A(a1, NTL - 1);
    p1A = __builtin_amdgcn_mfma_f32_32x32x16_bf16(a1, bf0, zacc, 0, 0, 0);
    p1B = __builtin_amdgcn_mfma_f32_32x32x16_bf16(a1, bf1, zacc, 0, 0, 0);
    accm0 = treemin16(p0A, accm0);
    accm1 = treemin16(p0B, accm1);
    accm0 = treemin16(p1A, accm0);
    accm1 = treemin16(p1B, accm1);
#undef LOAD_A

    // combine row-halves; store per-(seg,col) min (plain store, no atomics)
    {
        int v = imin(accm0, __shfl_xor(accm0, 32, 64));
        if (lane < 32)
            partial[((size_t)bd * SEG + seg) * NPTS + colbase + lane] = (unsigned int)v;
        int w = imin(accm1, __shfl_xor(accm1, 32, 64));
        if (lane < 32)
            partial[((size_t)bd * SEG + seg) * NPTS + colbase + 32 + lane] = (unsigned int)w;
    }
}

// Pass 2: 131072 (bd,col) slots; min over SEG=2 slices, sum, int64 fixed-point
// atomicAdd (bitwise deterministic); last block writes out = total/(B*N) - 2.
__global__ __launch_bounds__(NT)
void chamfer_comb_kernel(const unsigned int* __restrict__ partial,
                         unsigned long long* __restrict__ acc,
                         float* __restrict__ out)
{
    __shared__ float s_red[NT];
    const int s = (int)blockIdx.x * NT + (int)threadIdx.x;   // 4 cols of one bd
    const int f  = s * 4;
    const int bd = f >> 12;
    const int col = f & 4095;
    const size_t base0 = (size_t)bd * 2 * NPTS + col;
    const uint4 pa = *(const uint4*)&partial[base0];
    const uint4 pb = *(const uint4*)&partial[base0 + NPTS];
    float sum = __uint_as_float(imin((int)pa.x, (int)pb.x))
              + __uint_as_float(imin((int)pa.y, (int)pb.y))
              + __uint_as_float(imin((int)pa.z, (int)pb.z))
              + __uint_as_float(imin((int)pa.w, (int)pb.w));
    s_red[threadIdx.x] = sum;
    __syncthreads();
#pragma unroll
    for (int st = NT / 2; st > 0; st >>= 1) {
        if ((int)threadIdx.x < st) s_red[threadIdx.x] += s_red[threadIdx.x + st];
        __syncthreads();
    }
    if (threadIdx.x == 0) {
        const long long fx = (long long)llrint((double)s_red[0] * 4294967296.0);
        atomicAdd(&acc[0], (unsigned long long)fx);
        __threadfence();
        const unsigned long long t = atomicAdd(&acc[1], 1ULL);
        if (t == (unsigned long long)(NCOMB - 1)) {
            const unsigned long long total = atomicAdd(&acc[0], 0ULL);
            const double v = (double)(long long)total *
                             (1.0 / 4294967296.0) * (1.0 / (double)(BQ * NPTS)) - 2.0;
            out[0] = (float)v;
        }
    }
}

extern "C" void kernel_launch(void* const* d_in, const int* in_sizes, int n_in,
                              void* d_out, int out_size, void* d_ws, size_t ws_size,
                              hipStream_t stream)
{
    const float* preds = (const float*)d_in[0];
    const float* gts   = (const float*)d_in[1];
    float* out = (float*)d_out;
    unsigned int* partial = (unsigned int*)d_ws;                 // 32*2*4096 u32 = 1 MB
    unsigned long long* acc =
        (unsigned long long*)(partial + (size_t)2 * BQ * SEG * NPTS);

    dim3 grid1(NPTS / BCOLS, SEG, 2 * BQ);   // (16, 2, 32) = 1024 blocks, 4/CU
    chamfer_mfma_kernel<<<grid1, NT, 0, stream>>>(preds, gts, partial, acc);
    chamfer_comb_kernel<<<NCOMB, NT, 0, stream>>>(partial, acc, out);
}

// Round 17
// 27.787 us; speedup vs baseline: 3.8787x; 1.0353x over previous
//
#include <hip/hip_runtime.h>

#define NPTS   4096
#define BQ     16
#define NT     256               // 4 waves per block
#define SEG    2                 // inner segments
#define SEGN   (NPTS / SEG)      // 2048 inner points per block
#define NTL    (SEGN / 32)       // 64 tiles of 32 points
#define WC     4                 // col-tiles per wave (1 ds_read feeds 4 MFMA)
#define BCOLS  512               // cols per block (4 waves x 128)
#define NCOMB  128

typedef short bhalf8   __attribute__((ext_vector_type(8)));   // 8 bf16 (4 VGPRs)
typedef float floatx16 __attribute__((ext_vector_type(16)));  // 32x32 MFMA acc

__device__ __forceinline__ short f2bf(float f) {
    unsigned u = __float_as_uint(f);
    unsigned r = (u + 0x7FFFu + ((u >> 16) & 1u)) >> 16;   // RNE
    return (short)r;
}
__device__ __forceinline__ float bf2f(short s) {
    return __uint_as_float(((unsigned)(unsigned short)s) << 16);
}
__device__ __forceinline__ int imin(int a, int b) { return a < b ? a : b; }

__device__ __forceinline__ int treemin16(const floatx16 c, int accm) {
    const int x0  = __float_as_int(c[0]),  x1  = __float_as_int(c[1]);
    const int x2  = __float_as_int(c[2]),  x3  = __float_as_int(c[3]);
    const int x4  = __float_as_int(c[4]),  x5  = __float_as_int(c[5]);
    const int x6  = __float_as_int(c[6]),  x7  = __float_as_int(c[7]);
    const int x8  = __float_as_int(c[8]),  x9  = __float_as_int(c[9]);
    const int x10 = __float_as_int(c[10]), x11 = __float_as_int(c[11]);
    const int x12 = __float_as_int(c[12]), x13 = __float_as_int(c[13]);
    const int x14 = __float_as_int(c[14]), x15 = __float_as_int(c[15]);
    const int ta = imin(imin(x0,  x1),  x2);
    const int tb = imin(imin(x3,  x4),  x5);
    const int tc = imin(imin(x6,  x7),  x8);
    const int td = imin(imin(x9,  x10), x11);
    const int te = imin(imin(x12, x13), x14);
    const int tf = imin(imin(ta, tb), x15);
    const int tg = imin(imin(tc, td), te);
    return imin(imin(tf, tg), accm);
}

// Pass 1: MFMA 32x32x16 split-bf16 (verified math: D = dist2 + 1, positive ->
// int-bit min). Joint fix attempt: WC=4 (ds_read amortized over 4 MFMAs) +
// 2-stage static-name pipelined consume (tree of tile t after MFMAs of t+1)
// + __launch_bounds__(256,2) (256-VGPR budget: ~165 live regs stay VGPR,
// no AGPR move tax). grid (8, 2, 32) = 512 blocks, 2/CU (8 waves/CU).
__global__ __launch_bounds__(NT, 2)
void chamfer_mfma_kernel(const float* __restrict__ preds,
                         const float* __restrict__ gts,
                         unsigned int* __restrict__ partial,
                         unsigned long long* __restrict__ acc)
{
    __shared__ bhalf8 s_frag[NTL * 32];   // 32 KB

    const int tid = (int)threadIdx.x;
    const int cb  = blockIdx.x;   // 0..7
    const int seg = blockIdx.y;   // 0..1
    const int bd  = blockIdx.z;   // 0..31
    const int dir = bd >> 4;
    const int b   = bd & 15;

    if (cb == 0 && seg == 0 && bd == 0 && tid < 2)
        acc[tid] = 0ULL;   // [0]=fixed-point sum, [1]=ticket

    const float* outer = (dir == 0) ? preds : gts;
    const float* inner = (dir == 0) ? gts   : preds;
    const float* ob = outer + (size_t)b * NPTS * 3;
    const float* ib = inner + (size_t)b * NPTS * 3 + (size_t)seg * SEGN * 3;

    const short one = (short)0x3F80;   // bf16 1.0

    // ---- stage this segment's inner points (e0 form) ----
    for (int p = tid; p < SEGN; p += NT) {
        const float x0 = ib[p * 3 + 0], x1 = ib[p * 3 + 1], x2 = ib[p * 3 + 2];
        const float a0 = -2.0f * x0, a1 = -2.0f * x1, a2 = -2.0f * x2;
        const short h0 = f2bf(a0), h1 = f2bf(a1), h2 = f2bf(a2);
        const short l0 = f2bf(a0 - bf2f(h0));
        const short l1 = f2bf(a1 - bf2f(h1));
        const short l2 = f2bf(a2 - bf2f(h2));
        const float xx = x0 * x0 + x1 * x1 + x2 * x2;
        const short xh = f2bf(xx);
        const short xl = f2bf(xx - bf2f(xh));
        bhalf8 e0;
        e0[0] = h0; e0[1] = h1; e0[2] = h2; e0[3] = l0;
        e0[4] = l1; e0[5] = l2; e0[6] = xh; e0[7] = xl;
        s_frag[(p >> 5) * 32 + (p & 31)] = e0;
    }

    const int wv   = tid >> 6;           // 0..3
    const int lane = tid & 63;
    const int g    = lane >> 5;          // k-group 0..1
    const int colbase = cb * BCOLS + wv * (WC * 32);

    // ---- persistent B fragments: 4 col-tiles per wave (static names) ----
    bhalf8 bf0, bf1, bf2, bf3;
#pragma unroll
    for (int k = 0; k < WC; ++k) {
        const int col = colbase + k * 32 + (lane & 31);
        const float y0 = ob[col * 3 + 0], y1 = ob[col * 3 + 1], y2 = ob[col * 3 + 2];
        const short h0 = f2bf(y0), h1 = f2bf(y1), h2 = f2bf(y2);
        bhalf8 f;
        if (g == 0) {          // k 0-7: [yh(3), yh(3), 1, 1]
            f[0] = h0; f[1] = h1; f[2] = h2; f[3] = h0; f[4] = h1; f[5] = h2;
            f[6] = one; f[7] = one;
        } else {               // k 8-15: [yl(3), yl(3), vh, vl], v = yy+1
            const short q0 = f2bf(y0 - bf2f(h0));
            const short q1 = f2bf(y1 - bf2f(h1));
            const short q2 = f2bf(y2 - bf2f(h2));
            const float v = y0 * y0 + y1 * y1 + y2 * y2 + 1.0f;
            const short vh = f2bf(v);
            const short vl = f2bf(v - bf2f(vh));
            f[0] = q0; f[1] = q1; f[2] = q2; f[3] = q0; f[4] = q1; f[5] = q2;
            f[6] = vh; f[7] = vl;
        }
        if (k == 0) bf0 = f; else if (k == 1) bf1 = f;
        else if (k == 2) bf2 = f; else bf3 = f;
    }
    __syncthreads();

    int accm0 = 0x7F7F7F7F, accm1 = 0x7F7F7F7F;
    int accm2 = 0x7F7F7F7F, accm3 = 0x7F7F7F7F;
    const floatx16 zacc = {0,0,0,0,0,0,0,0,0,0,0,0,0,0,0,0};
    const int onepair = 0x3F803F80;
    const int arow = lane & 31;

#define LOAD_A(dst, t)                                   \
    {                                                    \
        union { bhalf8 v; int4 i; } au_;                 \
        au_.v = s_frag[(t) * 32 + arow];                 \
        if (lane >= 32) au_.i.w = onepair;               \
        dst = au_.v;                                     \
    }
#define MFMA4(pA, pB, pC, pD, a)                                            \
    pA = __builtin_amdgcn_mfma_f32_32x32x16_bf16(a, bf0, zacc, 0, 0, 0);    \
    pB = __builtin_amdgcn_mfma_f32_32x32x16_bf16(a, bf1, zacc, 0, 0, 0);    \
    pC = __builtin_amdgcn_mfma_f32_32x32x16_bf16(a, bf2, zacc, 0, 0, 0);    \
    pD = __builtin_amdgcn_mfma_f32_32x32x16_bf16(a, bf3, zacc, 0, 0, 0);
#define CONSUME(pA, pB, pC, pD)                                             \
    accm0 = treemin16(pA, accm0);                                           \
    accm1 = treemin16(pB, accm1);                                           \
    accm2 = treemin16(pC, accm2);                                           \
    accm3 = treemin16(pD, accm3);

    // ---- software-pipelined main loop (consume deferred one tile) ----
    bhalf8 a0, a1;
    floatx16 p0A, p0B, p0C, p0D, p1A, p1B, p1C, p1D;

    LOAD_A(a0, 0);
    MFMA4(p0A, p0B, p0C, p0D, a0)

#pragma unroll 1
    for (int t = 1; t < NTL - 1; t += 2) {
        LOAD_A(a1, t);
        MFMA4(p1A, p1B, p1C, p1D, a1)
        CONSUME(p0A, p0B, p0C, p0D)
        LOAD_A(a0, t + 1);
        MFMA4(p0A, p0B, p0C, p0D, a0)
        CONSUME(p1A, p1B, p1C, p1D)
    }
    LOAD_A(a1, NTL - 1);
    MFMA4(p1A, p1B, p1C, p1D, a1)
    CONSUME(p0A, p0B, p0C, p0D)
    CONSUME(p1A, p1B, p1C, p1D)
#undef LOAD_A
#undef MFMA4
#undef CONSUME

    // combine row-halves; store per-(seg,col) min (plain store, no atomics)
    const size_t pb = ((size_t)bd * SEG + seg) * NPTS + colbase;
    {
        int v0 = imin(accm0, __shfl_xor(accm0, 32, 64));
        int v1 = imin(accm1, __shfl_xor(accm1, 32, 64));
        int v2 = imin(accm2, __shfl_xor(accm2, 32, 64));
        int v3 = imin(accm3, __shfl_xor(accm3, 32, 64));
        if (lane < 32) {
            partial[pb + lane]      = (unsigned int)v0;
            partial[pb + 32 + lane] = (unsigned int)v1;
            partial[pb + 64 + lane] = (unsigned int)v2;
            partial[pb + 96 + lane] = (unsigned int)v3;
        }
    }
}

// Pass 2: 131072 (bd,col) slots; min over SEG=2 slices, sum, int64 fixed-point
// atomicAdd (bitwise deterministic); last block writes out = total/(B*N) - 2.
__global__ __launch_bounds__(NT)
void chamfer_comb_kernel(const unsigned int* __restrict__ partial,
                         unsigned long long* __restrict__ acc,
                         float* __restrict__ out)
{
    __shared__ float s_red[NT];
    const int s = (int)blockIdx.x * NT + (int)threadIdx.x;   // 4 cols of one bd
    const int f  = s * 4;
    const int bd = f >> 12;
    const int col = f & 4095;
    const size_t base0 = (size_t)bd * 2 * NPTS + col;
    const uint4 pa = *(const uint4*)&partial[base0];
    const uint4 pb = *(const uint4*)&partial[base0 + NPTS];
    float sum = __uint_as_float(imin((int)pa.x, (int)pb.x))
              + __uint_as_float(imin((int)pa.y, (int)pb.y))
              + __uint_as_float(imin((int)pa.z, (int)pb.z))
              + __uint_as_float(imin((int)pa.w, (int)pb.w));
    s_red[threadIdx.x] = sum;
    __syncthreads();
#pragma unroll
    for (int st = NT / 2; st > 0; st >>= 1) {
        if ((int)threadIdx.x < st) s_red[threadIdx.x] += s_red[threadIdx.x + st];
        __syncthreads();
    }
    if (threadIdx.x == 0) {
        const long long fx = (long long)llrint((double)s_red[0] * 4294967296.0);
        atomicAdd(&acc[0], (unsigned long long)fx);
        __threadfence();
        const unsigned long long t = atomicAdd(&acc[1], 1ULL);
        if (t == (unsigned long long)(NCOMB - 1)) {
            const unsigned long long total = atomicAdd(&acc[0], 0ULL);
            const double v = (double)(long long)total *
                             (1.0 / 4294967296.0) * (1.0 / (double)(BQ * NPTS)) - 2.0;
            out[0] = (float)v;
        }
    }
}

extern "C" void kernel_launch(void* const* d_in, const int* in_sizes, int n_in,
                              void* d_out, int out_size, void* d_ws, size_t ws_size,
                              hipStream_t stream)
{
    const float* preds = (const float*)d_in[0];
    const float* gts   = (const float*)d_in[1];
    float* out = (float*)d_out;
    unsigned int* partial = (unsigned int*)d_ws;                 // 32*2*4096 u32 = 1 MB
    unsigned long long* acc =
        (unsigned long long*)(partial + (size_t)2 * BQ * SEG * NPTS);

    dim3 grid1(NPTS / BCOLS, SEG, 2 * BQ);   // (8, 2, 32) = 512 blocks, 2/CU
    chamfer_mfma_kernel<<<grid1, NT, 0, stream>>>(preds, gts, partial, acc);
    chamfer_comb_kernel<<<NCOMB, NT, 0, stream>>>(partial, acc, out);
}